// Round 1
// baseline (1673.406 us; speedup 1.0000x reference)
//
#include <hip/hip_runtime.h>

typedef unsigned int u32;
typedef unsigned short u16;
typedef float f32x4 __attribute__((ext_vector_type(4)));
typedef __bf16 bf16x8 __attribute__((ext_vector_type(8)));
typedef u16 u16x8 __attribute__((ext_vector_type(8)));

__device__ __forceinline__ u16 f2bf(float f) {
    u32 u = __builtin_bit_cast(u32, f);
    u32 r = u + 0x7fffu + ((u >> 16) & 1u);
    return (u16)(r >> 16);
}
__device__ __forceinline__ float bf2f(u16 h) {
    return __builtin_bit_cast(float, ((u32)h) << 16);
}

// ---------------------------------------------------------------------------
// K0: convert w1 (96x384) -> w1T bf16 [384][96], w2 (384x96) -> w2T bf16 [96][384]
// ---------------------------------------------------------------------------
__global__ void prep_weights(const float* __restrict__ w1, const float* __restrict__ w2,
                             u16* __restrict__ wsT) {
    int i = blockIdx.x * 256 + threadIdx.x;
    if (i < 36864) {
        int n = i / 96, k = i - n * 96;          // w1T[n][k] = w1[k][n]
        wsT[i] = f2bf(w1[k * 384 + n]);
    } else if (i < 73728) {
        int i2 = i - 36864;
        int c = i2 / 384, hh = i2 - c * 384;     // w2T[c][h] = w2[h][c]
        wsT[i] = f2bf(w2[hh * 96 + c]);
    }
}

// ---------------------------------------------------------------------------
// K1: depthwise 7x7x7 conv + bias, output bf16.
// Block: 256 thr = tz(4 d) x ty(8 h-pairs) x tx(8 w-groups of 8).
// LDS tile: 10 d-planes x 22 h-rows x 72 w floats, 16B row stagger (bank spread).
// PACKED==0: write u32-packed bf16 pairs into ws plane [c][P/2]
// PACKED==1: write bf16 into HIGH half of d_out's f32 words (same (c,p) word).
// ---------------------------------------------------------------------------
template<int PACKED>
__global__ __launch_bounds__(256) void dwconv(const float* __restrict__ x,
                                              const float* __restrict__ dww,
                                              const float* __restrict__ dwb,
                                              u32* cw, u16* o16) {
    __shared__ float tile[15880];                 // 10 * 1588 words = 63,520 B
    const int tid = threadIdx.x;
    const int bx = blockIdx.x, c = blockIdx.y, b = blockIdx.z;
    const int d0 = (bx >> 2) * 4, h0 = (bx & 3) * 16;
    const float* xc = x + ((size_t)(b * 96 + c)) * 262144;

    // fill LDS tile (zero-padded halo), rows staggered by ((rr>>1)&1)*4 words
    for (int i = tid; i < 15840; i += 256) {
        int pz = i / 1584;
        int rem = i - pz * 1584;
        int rr = rem / 72;
        int col = rem - rr * 72;
        int dd = d0 + pz - 3, hh = h0 + rr - 3, ww = col - 3;
        float v = 0.f;
        if (((unsigned)dd < 64u) && ((unsigned)hh < 64u) && ((unsigned)ww < 64u))
            v = xc[dd * 4096 + hh * 64 + ww];
        tile[pz * 1588 + rr * 72 + (((rr >> 1) & 1) << 2) + col] = v;
    }
    __syncthreads();

    const int tx = tid & 7, ty = (tid >> 3) & 7, tz = tid >> 6;
    const float* Wc = dww + c * 343;
    float a0[8], a1[8];
#pragma unroll
    for (int i = 0; i < 8; ++i) { a0[i] = 0.f; a1[i] = 0.f; }

    for (int kd = 0; kd < 7; ++kd) {
        const float* Wk = Wc + kd * 49;
        const int pb = (tz + kd) * 1588 + 8 * tx;
#pragma unroll
        for (int r = 0; r < 8; ++r) {
            const int rr = 2 * ty + r;
            const float* tp = tile + pb + rr * 72 + (((rr >> 1) & 1) << 2);
            float rb[16];
            *(f32x4*)&rb[0]  = *(const f32x4*)(tp);
            *(f32x4*)&rb[4]  = *(const f32x4*)(tp + 4);
            *(f32x4*)&rb[8]  = *(const f32x4*)(tp + 8);
            *(f32x4*)&rb[12] = *(const f32x4*)(tp + 12);
            if (r < 7) {                           // contributes to h (kh = r)
#pragma unroll
                for (int kw = 0; kw < 7; ++kw) {
                    float wv = Wk[r * 7 + kw];
#pragma unroll
                    for (int i = 0; i < 8; ++i) a0[i] += rb[kw + i] * wv;
                }
            }
            if (r > 0) {                           // contributes to h+1 (kh = r-1)
#pragma unroll
                for (int kw = 0; kw < 7; ++kw) {
                    float wv = Wk[(r - 1) * 7 + kw];
#pragma unroll
                    for (int i = 0; i < 8; ++i) a1[i] += rb[kw + i] * wv;
                }
            }
        }
    }

    const float bias = dwb[c];
    const int d = d0 + tz;
    const int hA = h0 + 2 * ty;
    if (PACKED == 0) {
        const int p = b * 262144 + d * 4096 + hA * 64 + 8 * tx;
        u32* dst = cw + c * 262144 + (p >> 1);
#pragma unroll
        for (int k = 0; k < 4; ++k)
            dst[k] = (u32)f2bf(a0[2 * k] + bias) | ((u32)f2bf(a0[2 * k + 1] + bias) << 16);
        u32* dst1 = dst + 32;                      // next h row
#pragma unroll
        for (int k = 0; k < 4; ++k)
            dst1[k] = (u32)f2bf(a1[2 * k] + bias) | ((u32)f2bf(a1[2 * k + 1] + bias) << 16);
    } else {
        size_t e = ((size_t)(b * 96 + c)) * 262144 + d * 4096 + hA * 64 + 8 * tx;
#pragma unroll
        for (int i = 0; i < 8; ++i) o16[2 * (e + i) + 1] = f2bf(a0[i] + bias);
#pragma unroll
        for (int i = 0; i < 8; ++i) o16[2 * (e + 64 + i) + 1] = f2bf(a1[i] + bias);
    }
}

// ---------------------------------------------------------------------------
// K2: LN + MLP (bf16 MFMA) + gamma + residual. 64 positions / block, 256 thr.
// CWP: 0 = conv-out in ws (u32 bf16-pairs, [c][P/2]); 1 = hi-half of d_out words.
// WF : 0 = bf16 weights from ws; 1 = transpose f32 weights on the fly (fallback).
// ---------------------------------------------------------------------------
template<int CWP, int WF>
__global__ __launch_bounds__(256) void mlp_kernel(const void* cwsrc,
                                                  const u16* w1T16, const u16* w2T16,
                                                  const float* w1f, const float* w2f,
                                                  const float* lng, const float* lnb,
                                                  const float* b1g, const float* b2g,
                                                  const float* gam, const float* x,
                                                  float* out) {
    __shared__ __align__(16) unsigned char smem[52736];
    u16* A  = (u16*)(smem);                 // [64][104] bf16 (normed activations)
    u16* B1 = (u16*)(smem + 13312);         // [64][104] W1T chunk [n][k=96]
    u16* B2 = (u16*)(smem + 26624);         // [96][72]  W2T chunk [c][k=64]
    u16* Hs = (u16*)(smem + 40448);         // [64][72]  hidden chunk [p][n=64]
    float* prm = (float*)(smem + 49664);    // lng 0..95 | lnb | b2 | gamma | b1[384]

    const int tid = threadIdx.x;
    const int p0 = blockIdx.x * 64;
    const int b = p0 >> 18;
    const int prel0 = p0 & 262143;

    for (int i = tid; i < 768; i += 256) {
        float v;
        if (i < 96) v = lng[i];
        else if (i < 192) v = lnb[i - 96];
        else if (i < 288) v = b2g[i - 192];
        else if (i < 384) v = gam[i - 288];
        else v = b1g[i - 384];
        prm[i] = v;
    }

    if (CWP == 0) {
        const u32* cws = (const u32*)cwsrc;
        for (int i = tid; i < 3072; i += 256) {
            int c = i >> 5, q = i & 31;
            u32 v = cws[c * 262144 + (p0 >> 1) + q];
            A[(2 * q) * 104 + c] = (u16)(v & 0xffffu);
            A[(2 * q + 1) * 104 + c] = (u16)(v >> 16);
        }
    } else {
        const u32* ow = (const u32*)cwsrc;
        for (int i = tid; i < 6144; i += 256) {
            int c = i >> 6, t = i & 63;
            u32 v = ow[((size_t)(b * 96 + c)) * 262144 + prel0 + t];
            A[t * 104 + c] = (u16)(v >> 16);
        }
    }
    __syncthreads();

    // LayerNorm in place: 4 lanes per position, 24 channels each
    {
        const int pos = tid >> 2, qd = tid & 3;
        const u16* Ar = A + pos * 104 + qd * 24;
        u16x8 r0 = *(const u16x8*)(Ar);
        u16x8 r1 = *(const u16x8*)(Ar + 8);
        u16x8 r2 = *(const u16x8*)(Ar + 16);
        float v[24];
#pragma unroll
        for (int t = 0; t < 8; ++t) { v[t] = bf2f(r0[t]); v[t + 8] = bf2f(r1[t]); v[t + 16] = bf2f(r2[t]); }
        float s = 0.f, sq = 0.f;
#pragma unroll
        for (int t = 0; t < 24; ++t) { s += v[t]; sq += v[t] * v[t]; }
        s += __shfl_xor(s, 1);  sq += __shfl_xor(sq, 1);
        s += __shfl_xor(s, 2);  sq += __shfl_xor(sq, 2);
        float mu = s * (1.f / 96.f);
        float var = sq * (1.f / 96.f) - mu * mu;
        float rstd = rsqrtf(var + 1e-5f);
        const int cb = qd * 24;
        u32* Aw = (u32*)(A + pos * 104 + cb);
#pragma unroll
        for (int t = 0; t < 12; ++t) {
            float y0 = (v[2 * t] - mu) * rstd * prm[cb + 2 * t] + prm[96 + cb + 2 * t];
            float y1 = (v[2 * t + 1] - mu) * rstd * prm[cb + 2 * t + 1] + prm[96 + cb + 2 * t + 1];
            Aw[t] = (u32)f2bf(y0) | ((u32)f2bf(y1) << 16);
        }
    }
    __syncthreads();

    const int lane = tid & 63, wv = tid >> 6;
    const int lrow = lane & 15, g = lane >> 4;
    const int m0 = wv * 16;
    const f32x4 zero = {0.f, 0.f, 0.f, 0.f};

    bf16x8 aF[3];
#pragma unroll
    for (int kk = 0; kk < 3; ++kk)
        aF[kk] = *(const bf16x8*)(A + (m0 + lrow) * 104 + kk * 32 + g * 8);

    f32x4 acc2[6];
#pragma unroll
    for (int i = 0; i < 6; ++i) acc2[i] = zero;

    for (int j = 0; j < 6; ++j) {
        if (WF == 0) {
            const u32* w1u = (const u32*)w1T16;
            const u32* w2u = (const u32*)w2T16;
            for (int i = tid; i < 3072; i += 256) {
                int nl = i / 48, q = i - nl * 48;
                *(u32*)(B1 + nl * 104 + 2 * q) = w1u[(j * 64 + nl) * 48 + q];
            }
            for (int i = tid; i < 3072; i += 256) {
                int nl = i >> 5, q = i & 31;
                *(u32*)(B2 + nl * 72 + 2 * q) = w2u[nl * 192 + j * 32 + q];
            }
        } else {
            for (int i = tid; i < 6144; i += 256) {
                int nl = i / 96, k = i - nl * 96;
                B1[nl * 104 + k] = f2bf(w1f[k * 384 + j * 64 + nl]);
            }
            for (int i = tid; i < 6144; i += 256) {
                int nl = i >> 6, k = i & 63;
                B2[nl * 72 + k] = f2bf(w2f[(j * 64 + k) * 96 + nl]);
            }
        }
        __syncthreads();

        // GEMM1: C1[64p x 64n] = A[64x96] @ W1chunk
        f32x4 c1[4];
#pragma unroll
        for (int nt = 0; nt < 4; ++nt) {
            c1[nt] = zero;
#pragma unroll
            for (int kk = 0; kk < 3; ++kk) {
                bf16x8 bF = *(const bf16x8*)(B1 + (nt * 16 + lrow) * 104 + kk * 32 + g * 8);
                c1[nt] = __builtin_amdgcn_mfma_f32_16x16x32_bf16(aF[kk], bF, c1[nt], 0, 0, 0);
            }
        }
        // bias + exact GELU -> Hs (bf16)
#pragma unroll
        for (int nt = 0; nt < 4; ++nt) {
            int nloc = nt * 16 + lrow;
            float b1v = prm[384 + j * 64 + nloc];
#pragma unroll
            for (int r = 0; r < 4; ++r) {
                float vv = c1[nt][r] + b1v;
                float ge = 0.5f * vv * (1.f + erff(vv * 0.70710678118654752f));
                Hs[(m0 + g * 4 + r) * 72 + nloc] = f2bf(ge);
            }
        }
        __syncthreads();

        // GEMM2: acc2 += H[64x64] @ W2chunk[64x96]
        bf16x8 hF[2];
#pragma unroll
        for (int kk = 0; kk < 2; ++kk)
            hF[kk] = *(const bf16x8*)(Hs + (m0 + lrow) * 72 + kk * 32 + g * 8);
#pragma unroll
        for (int nt = 0; nt < 6; ++nt) {
#pragma unroll
            for (int kk = 0; kk < 2; ++kk) {
                bf16x8 bF = *(const bf16x8*)(B2 + (nt * 16 + lrow) * 72 + kk * 32 + g * 8);
                acc2[nt] = __builtin_amdgcn_mfma_f32_16x16x32_bf16(hF[kk], bF, acc2[nt], 0, 0, 0);
            }
        }
        __syncthreads();
    }

    // epilogue: transpose via LDS (stride 97 -> conflict-free), coalesced out
    float* O = (float*)smem;                  // [64][97] overlays A+B1 (dead)
#pragma unroll
    for (int nt = 0; nt < 6; ++nt)
#pragma unroll
        for (int r = 0; r < 4; ++r)
            O[(m0 + g * 4 + r) * 97 + nt * 16 + lrow] = acc2[nt][r];
    __syncthreads();

    for (int i = tid; i < 6144; i += 256) {
        int c = i >> 6, t = i & 63;
        float val = O[t * 97 + c];
        size_t xi = ((size_t)(b * 96 + c)) * 262144 + prel0 + t;
        out[xi] = (val + prm[192 + c]) * prm[288 + c] + x[xi];
    }
}

// ---------------------------------------------------------------------------
extern "C" void kernel_launch(void* const* d_in, const int* in_sizes, int n_in,
                              void* d_out, int out_size, void* d_ws, size_t ws_size,
                              hipStream_t stream) {
    const float* x   = (const float*)d_in[0];
    const float* dww = (const float*)d_in[1];
    const float* dwb = (const float*)d_in[2];
    const float* lng = (const float*)d_in[3];
    const float* lnb = (const float*)d_in[4];
    const float* w1  = (const float*)d_in[5];
    const float* b1  = (const float*)d_in[6];
    const float* w2  = (const float*)d_in[7];
    const float* b2  = (const float*)d_in[8];
    const float* gam = (const float*)d_in[9];
    float* out = (float*)d_out;

    const size_t NEED_W = 147456;                       // bf16 w1T + w2T
    const size_t NEED_FULL = NEED_W + 100663296ull;     // + bf16 conv-out
    const bool wsW = ws_size >= NEED_W;
    const bool wsCW = ws_size >= NEED_FULL;

    u16* wsT = (u16*)d_ws;
    u32* cw = (u32*)((char*)d_ws + NEED_W);

    if (wsW)
        hipLaunchKernelGGL(prep_weights, dim3(288), dim3(256), 0, stream, w1, w2, wsT);

    dim3 g1(64, 96, 2), blk(256);
    if (wsCW)
        hipLaunchKernelGGL((dwconv<0>), g1, blk, 0, stream, x, dww, dwb, cw, (u16*)d_out);
    else
        hipLaunchKernelGGL((dwconv<1>), g1, blk, 0, stream, x, dww, dwb, cw, (u16*)d_out);

    dim3 g2(8192);
    if (wsCW)
        hipLaunchKernelGGL((mlp_kernel<0, 0>), g2, blk, 0, stream, (const void*)cw,
                           wsT, wsT + 36864, w1, w2, lng, lnb, b1, b2, gam, x, out);
    else if (wsW)
        hipLaunchKernelGGL((mlp_kernel<1, 0>), g2, blk, 0, stream, (const void*)d_out,
                           wsT, wsT + 36864, w1, w2, lng, lnb, b1, b2, gam, x, out);
    else
        hipLaunchKernelGGL((mlp_kernel<1, 1>), g2, blk, 0, stream, (const void*)d_out,
                           wsT, wsT + 36864, w1, w2, lng, lnb, b1, b2, gam, x, out);
}

// Round 2
// 1165.889 us; speedup vs baseline: 1.4353x; 1.4353x over previous
//
#include <hip/hip_runtime.h>

typedef unsigned int u32;
typedef unsigned short u16;
typedef float f32x4 __attribute__((ext_vector_type(4)));
typedef __bf16 bf16x8 __attribute__((ext_vector_type(8)));
typedef u16 u16x8 __attribute__((ext_vector_type(8)));
typedef u32 u32x4 __attribute__((ext_vector_type(4)));
typedef _Float16 hf2 __attribute__((ext_vector_type(2)));

__device__ __forceinline__ u16 f2bf(float f) {
    u32 u = __builtin_bit_cast(u32, f);
    u32 r = u + 0x7fffu + ((u >> 16) & 1u);
    return (u16)(r >> 16);
}
__device__ __forceinline__ u16 f2bf_rne(float f) {       // single v_cvt
    return __builtin_bit_cast(u16, (__bf16)f);
}
__device__ __forceinline__ float bf2f(u16 h) {
    return __builtin_bit_cast(float, ((u32)h) << 16);
}
__device__ __forceinline__ u32 pkh(float lo, float hi) { // pack 2xf16 (RTZ)
    return __builtin_bit_cast(u32, __builtin_amdgcn_cvt_pkrtz(lo, hi));
}
__device__ __forceinline__ hf2 ash(u32 v) { return __builtin_bit_cast(hf2, v); }

// ---------------------------------------------------------------------------
// K0: w1 (96x384) -> w1T bf16 [384][96]; w2 (384x96) -> w2T bf16 [96][384];
//     paired f16 conv weights wpair[c][kd][pr8][kw] (pr8 0..3 = a0-pairs,
//     4..7 = a1-pairs): a0 pair pr = (w[2pr],w[2pr+1]) over kh; a1 = (w[2pr-1],w[2pr]).
// ---------------------------------------------------------------------------
__global__ void prep_weights(const float* __restrict__ w1, const float* __restrict__ w2,
                             const float* __restrict__ dww,
                             u16* __restrict__ wsT, u32* __restrict__ wpair) {
    int i = blockIdx.x * 256 + threadIdx.x;
    if (i < 36864) {
        int n = i / 96, k = i - n * 96;          // w1T[n][k] = w1[k][n]
        wsT[i] = f2bf(w1[k * 384 + n]);
    } else if (i < 73728) {
        int i2 = i - 36864;
        int c = i2 / 384, hh = i2 - c * 384;     // w2T[c][h] = w2[h][c]
        wsT[i] = f2bf(w2[hh * 96 + c]);
    } else if (i < 111360) {
        int j = i - 73728;
        int c = j / 392, r = j - c * 392;
        int kd = r / 56, q = r - kd * 56;
        int pr8 = q / 7, kw = q - pr8 * 7;
        const float* Wk = dww + c * 343 + kd * 49;
        float lo, hi;
        if (pr8 < 4) {                            // a0: kh = 2pr, 2pr+1
            int pr = pr8;
            lo = Wk[(2 * pr) * 7 + kw];
            hi = (2 * pr + 1 < 7) ? Wk[(2 * pr + 1) * 7 + kw] : 0.f;
        } else {                                  // a1: kh = 2pr-1, 2pr
            int pr = pr8 - 4;
            lo = (2 * pr - 1 >= 0) ? Wk[(2 * pr - 1) * 7 + kw] : 0.f;
            hi = Wk[(2 * pr) * 7 + kw];
        }
        wpair[j] = pkh(lo, hi);
    }
}

// ---------------------------------------------------------------------------
// K1: depthwise 7x7x7 conv + bias via v_dot2_f32_f16, kh-paired f16x2 LDS tile.
// Block 256 thr = tz(4 d) x ty(8 h-pairs) x tx(8 w-groups of 8).
// Tile: 10 planes x 11 h-pair-rows x 72 f16x2 (stride), 31,680 B.
// Granule-XOR swizzle (16B granules) so b128 reads cover all 32 banks.
// PACKED==0: write u32-packed bf16 pairs into ws plane [c][P/2]
// PACKED==1: write bf16 into HIGH half of d_out's f32 words.
// WP==1: paired weights from ws table (uniform s_load); WP==0: build from dww.
// ---------------------------------------------------------------------------
template<int PACKED, int WP>
__global__ __launch_bounds__(256, 5) void dwconv(const float* __restrict__ x,
                                                 const float* __restrict__ dww,
                                                 const float* __restrict__ dwb,
                                                 const u32* __restrict__ wpair,
                                                 u32* cw, u16* o16) {
    __shared__ u32 tile32[7920];                  // 10 * 792
    const int tid = threadIdx.x;
    const int bx = blockIdx.x, c = blockIdx.y, b = blockIdx.z;
    const int d0 = (bx >> 2) * 4, h0 = (bx & 3) * 16;
    const float* xc = x + ((size_t)(b * 96 + c)) * 262144;

    // stage halo tile as (row 2r, row 2r+1) f16 pairs; swizzled granules
    for (int i = tid; i < 7700; i += 256) {
        int pz = i / 770;
        int rem = i - pz * 770;
        int r2 = rem / 70;
        int col = rem - r2 * 70;
        int d = d0 + pz - 3, h = h0 + 2 * r2 - 3, w = col - 3;
        float lo = 0.f, hi = 0.f;
        if (((unsigned)d < 64u) && ((unsigned)w < 64u)) {
            int base = d * 4096 + h * 64 + w;
            if ((unsigned)h < 64u) lo = xc[base];
            if ((unsigned)(h + 1) < 64u) hi = xc[base + 64];
        }
        int a = pz * 792 + r2 * 72 + col;
        int aw = ((((a >> 2) ^ ((a >> 5) & 1)) << 2)) | (a & 3);
        tile32[aw] = pkh(lo, hi);
    }
    __syncthreads();

    const int tx = tid & 7, ty = (tid >> 3) & 7, tz = tid >> 6;
    float a0[8], a1[8];
#pragma unroll
    for (int i = 0; i < 8; ++i) { a0[i] = 0.f; a1[i] = 0.f; }

    for (int kd = 0; kd < 7; ++kd) {
        const u32* wpk = wpair + (c * 7 + kd) * 56;   // uniform -> s_load
        const float* Wk = dww + c * 343 + kd * 49;    // (WP==0 fallback)
        const int pz = tz + kd;
#pragma unroll
        for (int pr = 0; pr < 4; ++pr) {
            u32 wa[7], wb[7];
            if (WP == 1) {
#pragma unroll
                for (int kw = 0; kw < 7; ++kw) {
                    wa[kw] = wpk[pr * 7 + kw];
                    wb[kw] = wpk[(pr + 4) * 7 + kw];
                }
            } else {
#pragma unroll
                for (int kw = 0; kw < 7; ++kw) {
                    float la = Wk[(2 * pr) * 7 + kw];
                    float ha = (2 * pr + 1 < 7) ? Wk[(2 * pr + 1) * 7 + kw] : 0.f;
                    float lb = (2 * pr - 1 >= 0) ? Wk[(2 * pr - 1) * 7 + kw] : 0.f;
                    wa[kw] = pkh(la, ha);
                    wb[kw] = pkh(lb, la);
                }
            }
            const int g0 = pz * 198 + (ty + pr) * 18 + (tx << 1);  // granules
            u32 rb[16];
#pragma unroll
            for (int k = 0; k < 4; ++k) {
                int g = g0 + k;
                int ga = (g ^ ((g >> 3) & 1)) << 2;
                *(u32x4*)&rb[4 * k] = *(const u32x4*)(tile32 + ga);
            }
#pragma unroll
            for (int kw = 0; kw < 7; ++kw) {
                hf2 va = ash(wa[kw]), vb = ash(wb[kw]);
#pragma unroll
                for (int i = 0; i < 8; ++i) {
                    a0[i] = __builtin_amdgcn_fdot2(ash(rb[kw + i]), va, a0[i], false);
                    a1[i] = __builtin_amdgcn_fdot2(ash(rb[kw + i]), vb, a1[i], false);
                }
            }
        }
    }

    const float bias = dwb[c];
    const int d = d0 + tz;
    const int hA = h0 + 2 * ty;
    if (PACKED == 0) {
        const int p = b * 262144 + d * 4096 + hA * 64 + 8 * tx;
        u32* dst = cw + c * 262144 + (p >> 1);
#pragma unroll
        for (int k = 0; k < 4; ++k)
            dst[k] = (u32)f2bf_rne(a0[2 * k] + bias) | ((u32)f2bf_rne(a0[2 * k + 1] + bias) << 16);
        u32* dst1 = dst + 32;                      // next h row
#pragma unroll
        for (int k = 0; k < 4; ++k)
            dst1[k] = (u32)f2bf_rne(a1[2 * k] + bias) | ((u32)f2bf_rne(a1[2 * k + 1] + bias) << 16);
    } else {
        size_t e = ((size_t)(b * 96 + c)) * 262144 + d * 4096 + hA * 64 + 8 * tx;
#pragma unroll
        for (int i = 0; i < 8; ++i) o16[2 * (e + i) + 1] = f2bf_rne(a0[i] + bias);
#pragma unroll
        for (int i = 0; i < 8; ++i) o16[2 * (e + 64 + i) + 1] = f2bf_rne(a1[i] + bias);
    }
}

// ---------------------------------------------------------------------------
// K2: LN + MLP (bf16 MFMA) + gamma + residual. 64 positions / block, 256 thr.
// CWP: 0 = conv-out in ws (u32 bf16-pairs, [c][P/2]); 1 = hi-half of d_out words.
// WF : 0 = bf16 weights from ws; 1 = transpose f32 weights on the fly (fallback).
// ---------------------------------------------------------------------------
template<int CWP, int WF>
__global__ __launch_bounds__(256) void mlp_kernel(const void* cwsrc,
                                                  const u16* w1T16, const u16* w2T16,
                                                  const float* w1f, const float* w2f,
                                                  const float* lng, const float* lnb,
                                                  const float* b1g, const float* b2g,
                                                  const float* gam, const float* x,
                                                  float* out) {
    __shared__ __align__(16) unsigned char smem[52736];
    u16* A  = (u16*)(smem);                 // [64][104] bf16 (normed activations)
    u16* B1 = (u16*)(smem + 13312);         // [64][104] W1T chunk [n][k=96]
    u16* B2 = (u16*)(smem + 26624);         // [96][72]  W2T chunk [c][k=64]
    u16* Hs = (u16*)(smem + 40448);         // [64][72]  hidden chunk [p][n=64]
    float* prm = (float*)(smem + 49664);    // lng 0..95 | lnb | b2 | gamma | b1[384]

    const int tid = threadIdx.x;
    const int p0 = blockIdx.x * 64;
    const int b = p0 >> 18;
    const int prel0 = p0 & 262143;

    for (int i = tid; i < 768; i += 256) {
        float v;
        if (i < 96) v = lng[i];
        else if (i < 192) v = lnb[i - 96];
        else if (i < 288) v = b2g[i - 192];
        else if (i < 384) v = gam[i - 288];
        else v = b1g[i - 384];
        prm[i] = v;
    }

    if (CWP == 0) {
        const u32* cws = (const u32*)cwsrc;
        for (int i = tid; i < 3072; i += 256) {
            int c = i >> 5, q = i & 31;
            u32 v = cws[c * 262144 + (p0 >> 1) + q];
            A[(2 * q) * 104 + c] = (u16)(v & 0xffffu);
            A[(2 * q + 1) * 104 + c] = (u16)(v >> 16);
        }
    } else {
        const u32* ow = (const u32*)cwsrc;
        for (int i = tid; i < 6144; i += 256) {
            int c = i >> 6, t = i & 63;
            u32 v = ow[((size_t)(b * 96 + c)) * 262144 + prel0 + t];
            A[t * 104 + c] = (u16)(v >> 16);
        }
    }
    __syncthreads();

    // LayerNorm in place: 4 lanes per position, 24 channels each
    {
        const int pos = tid >> 2, qd = tid & 3;
        const u16* Ar = A + pos * 104 + qd * 24;
        u16x8 r0 = *(const u16x8*)(Ar);
        u16x8 r1 = *(const u16x8*)(Ar + 8);
        u16x8 r2 = *(const u16x8*)(Ar + 16);
        float v[24];
#pragma unroll
        for (int t = 0; t < 8; ++t) { v[t] = bf2f(r0[t]); v[t + 8] = bf2f(r1[t]); v[t + 16] = bf2f(r2[t]); }
        float s = 0.f, sq = 0.f;
#pragma unroll
        for (int t = 0; t < 24; ++t) { s += v[t]; sq += v[t] * v[t]; }
        s += __shfl_xor(s, 1);  sq += __shfl_xor(sq, 1);
        s += __shfl_xor(s, 2);  sq += __shfl_xor(sq, 2);
        float mu = s * (1.f / 96.f);
        float var = sq * (1.f / 96.f) - mu * mu;
        float rstd = rsqrtf(var + 1e-5f);
        const int cb = qd * 24;
        u32* Aw = (u32*)(A + pos * 104 + cb);
#pragma unroll
        for (int t = 0; t < 12; ++t) {
            float y0 = (v[2 * t] - mu) * rstd * prm[cb + 2 * t] + prm[96 + cb + 2 * t];
            float y1 = (v[2 * t + 1] - mu) * rstd * prm[cb + 2 * t + 1] + prm[96 + cb + 2 * t + 1];
            Aw[t] = (u32)f2bf_rne(y0) | ((u32)f2bf_rne(y1) << 16);
        }
    }
    __syncthreads();

    const int lane = tid & 63, wv = tid >> 6;
    const int lrow = lane & 15, g = lane >> 4;
    const int m0 = wv * 16;
    const f32x4 zero = {0.f, 0.f, 0.f, 0.f};

    bf16x8 aF[3];
#pragma unroll
    for (int kk = 0; kk < 3; ++kk)
        aF[kk] = *(const bf16x8*)(A + (m0 + lrow) * 104 + kk * 32 + g * 8);

    f32x4 acc2[6];
#pragma unroll
    for (int i = 0; i < 6; ++i) acc2[i] = zero;

    for (int j = 0; j < 6; ++j) {
        if (WF == 0) {
            const u32* w1u = (const u32*)w1T16;
            const u32* w2u = (const u32*)w2T16;
            for (int i = tid; i < 3072; i += 256) {
                int nl = i / 48, q = i - nl * 48;
                *(u32*)(B1 + nl * 104 + 2 * q) = w1u[(j * 64 + nl) * 48 + q];
            }
            for (int i = tid; i < 3072; i += 256) {
                int nl = i >> 5, q = i & 31;
                *(u32*)(B2 + nl * 72 + 2 * q) = w2u[nl * 192 + j * 32 + q];
            }
        } else {
            for (int i = tid; i < 6144; i += 256) {
                int nl = i / 96, k = i - nl * 96;
                B1[nl * 104 + k] = f2bf(w1f[k * 384 + j * 64 + nl]);
            }
            for (int i = tid; i < 6144; i += 256) {
                int nl = i >> 6, k = i & 63;
                B2[nl * 72 + k] = f2bf(w2f[(j * 64 + k) * 96 + nl]);
            }
        }
        __syncthreads();

        // GEMM1: C1[64p x 64n] = A[64x96] @ W1chunk
        f32x4 c1[4];
#pragma unroll
        for (int nt = 0; nt < 4; ++nt) {
            c1[nt] = zero;
#pragma unroll
            for (int kk = 0; kk < 3; ++kk) {
                bf16x8 bF = *(const bf16x8*)(B1 + (nt * 16 + lrow) * 104 + kk * 32 + g * 8);
                c1[nt] = __builtin_amdgcn_mfma_f32_16x16x32_bf16(aF[kk], bF, c1[nt], 0, 0, 0);
            }
        }
        // bias + fast sigmoid-GELU -> Hs (bf16); gamma=1e-6 makes approx error moot
#pragma unroll
        for (int nt = 0; nt < 4; ++nt) {
            int nloc = nt * 16 + lrow;
            float b1v = prm[384 + j * 64 + nloc];
#pragma unroll
            for (int r = 0; r < 4; ++r) {
                float vv = c1[nt][r] + b1v;
                float t = __builtin_amdgcn_exp2f(vv * -2.4554673f);
                float ge = vv * __builtin_amdgcn_rcpf(1.f + t);
                Hs[(m0 + g * 4 + r) * 72 + nloc] = f2bf_rne(ge);
            }
        }
        __syncthreads();

        // GEMM2: acc2 += H[64x64] @ W2chunk[64x96]
        bf16x8 hF[2];
#pragma unroll
        for (int kk = 0; kk < 2; ++kk)
            hF[kk] = *(const bf16x8*)(Hs + (m0 + lrow) * 72 + kk * 32 + g * 8);
#pragma unroll
        for (int nt = 0; nt < 6; ++nt) {
#pragma unroll
            for (int kk = 0; kk < 2; ++kk) {
                bf16x8 bF = *(const bf16x8*)(B2 + (nt * 16 + lrow) * 72 + kk * 32 + g * 8);
                acc2[nt] = __builtin_amdgcn_mfma_f32_16x16x32_bf16(hF[kk], bF, acc2[nt], 0, 0, 0);
            }
        }
        __syncthreads();
    }

    // epilogue: transpose via LDS (stride 97 -> conflict-free), coalesced out
    float* O = (float*)smem;                  // [64][97] overlays A+B1 (dead)
#pragma unroll
    for (int nt = 0; nt < 6; ++nt)
#pragma unroll
        for (int r = 0; r < 4; ++r)
            O[(m0 + g * 4 + r) * 97 + nt * 16 + lrow] = acc2[nt][r];
    __syncthreads();

    for (int i = tid; i < 6144; i += 256) {
        int c = i >> 6, t = i & 63;
        float val = O[t * 97 + c];
        size_t xi = ((size_t)(b * 96 + c)) * 262144 + prel0 + t;
        out[xi] = (val + prm[192 + c]) * prm[288 + c] + x[xi];
    }
}

// ---------------------------------------------------------------------------
extern "C" void kernel_launch(void* const* d_in, const int* in_sizes, int n_in,
                              void* d_out, int out_size, void* d_ws, size_t ws_size,
                              hipStream_t stream) {
    const float* x   = (const float*)d_in[0];
    const float* dww = (const float*)d_in[1];
    const float* dwb = (const float*)d_in[2];
    const float* lng = (const float*)d_in[3];
    const float* lnb = (const float*)d_in[4];
    const float* w1  = (const float*)d_in[5];
    const float* b1  = (const float*)d_in[6];
    const float* w2  = (const float*)d_in[7];
    const float* b2  = (const float*)d_in[8];
    const float* gam = (const float*)d_in[9];
    float* out = (float*)d_out;

    const size_t NEED_WT = 147456;                       // bf16 w1T + w2T
    const size_t NEED_WP = NEED_WT + 150528;             // + f16 conv weight pairs
    const size_t NEED_FULL = NEED_WP + 100663296ull;     // + bf16 conv-out
    const bool wsWT = ws_size >= NEED_WT;
    const bool wsWP = ws_size >= NEED_WP;
    const bool wsCW = ws_size >= NEED_FULL;

    u16* wsT = (u16*)d_ws;
    u32* wpair = (u32*)((char*)d_ws + NEED_WT);
    u32* cw = (u32*)((char*)d_ws + NEED_WP);

    if (wsWT)
        hipLaunchKernelGGL(prep_weights, dim3(wsWP ? 435 : 288), dim3(256), 0, stream,
                           w1, w2, dww, wsT, wpair);

    dim3 g1(64, 96, 2), blk(256);
    if (wsCW)
        hipLaunchKernelGGL((dwconv<0, 1>), g1, blk, 0, stream, x, dww, dwb, wpair, cw, (u16*)d_out);
    else if (wsWP)
        hipLaunchKernelGGL((dwconv<1, 1>), g1, blk, 0, stream, x, dww, dwb, wpair, cw, (u16*)d_out);
    else
        hipLaunchKernelGGL((dwconv<1, 0>), g1, blk, 0, stream, x, dww, dwb, wpair, cw, (u16*)d_out);

    dim3 g2(8192);
    if (wsCW)
        hipLaunchKernelGGL((mlp_kernel<0, 0>), g2, blk, 0, stream, (const void*)cw,
                           wsT, wsT + 36864, w1, w2, lng, lnb, b1, b2, gam, x, out);
    else if (wsWT)
        hipLaunchKernelGGL((mlp_kernel<1, 0>), g2, blk, 0, stream, (const void*)d_out,
                           wsT, wsT + 36864, w1, w2, lng, lnb, b1, b2, gam, x, out);
    else
        hipLaunchKernelGGL((mlp_kernel<1, 1>), g2, blk, 0, stream, (const void*)d_out,
                           wsT, wsT + 36864, w1, w2, lng, lnb, b1, b2, gam, x, out);
}

// Round 3
// 801.384 us; speedup vs baseline: 2.0881x; 1.4548x over previous
//
#include <hip/hip_runtime.h>

typedef unsigned int u32;
typedef unsigned short u16;
typedef unsigned long long u64;
typedef long i64;
typedef float f32x4 __attribute__((ext_vector_type(4)));
typedef u32 u32x4 __attribute__((ext_vector_type(4)));
typedef _Float16 hf2 __attribute__((ext_vector_type(2)));

__device__ __forceinline__ u16 f2bf_rne(float f) {
    return __builtin_bit_cast(u16, (__bf16)f);
}
__device__ __forceinline__ float bf2f(u16 h) {
    return __builtin_bit_cast(float, ((u32)h) << 16);
}
__device__ __forceinline__ u32 pkh(float lo, float hi) { // pack 2xf16 (RTZ)
    return __builtin_bit_cast(u32, __builtin_amdgcn_cvt_pkrtz(lo, hi));
}
__device__ __forceinline__ hf2 ash(u32 v) { return __builtin_bit_cast(hf2, v); }
__device__ __forceinline__ float gelu_fast(float v) {
    float t = __builtin_amdgcn_exp2f(v * -2.4554673f);
    return v * __builtin_amdgcn_rcpf(1.f + t);
}
__device__ __forceinline__ i64 mk64(u32 lo, u32 hi) {
    return (i64)(((u64)hi << 32) | (u64)lo);
}

// ---------------------------------------------------------------------------
// K0: prep. w1f8[n=384][c=96] = fp8(lng[c]*w1[c][n]);  w2f8[c=96][n=384] = fp8(w2[n][c]);
//     B1s[n] = b1[n] + sum_c lnb[c]*w1[c][n];  wpair = f16-paired conv weights.
// ---------------------------------------------------------------------------
__global__ void prep_weights(const float* __restrict__ w1, const float* __restrict__ w2,
                             const float* __restrict__ dww, const float* __restrict__ lng,
                             const float* __restrict__ lnb, const float* __restrict__ b1,
                             unsigned char* __restrict__ w1f8, unsigned char* __restrict__ w2f8,
                             float* __restrict__ B1s, u32* __restrict__ wpair) {
    int i = blockIdx.x * 256 + threadIdx.x;
    if (i < 18432) {                              // w1f8 pairs
        int n = i / 48, cp = i - n * 48;
        float a = lng[2 * cp] * w1[(2 * cp) * 384 + n];
        float b = lng[2 * cp + 1] * w1[(2 * cp + 1) * 384 + n];
        u32 w = (u32)__builtin_amdgcn_cvt_pk_fp8_f32(a, b, 0, false);
        *(u16*)(w1f8 + n * 96 + 2 * cp) = (u16)w;
    } else if (i < 36864) {                       // w2f8 pairs
        int i2 = i - 18432;
        int c = i2 / 192, np = i2 - c * 192;
        float a = w2[(2 * np) * 96 + c];
        float b = w2[(2 * np + 1) * 96 + c];
        u32 w = (u32)__builtin_amdgcn_cvt_pk_fp8_f32(a, b, 0, false);
        *(u16*)(w2f8 + c * 384 + 2 * np) = (u16)w;
    } else if (i < 37248) {                       // B1s
        int n = i - 36864;
        float s = b1[n];
        for (int c = 0; c < 96; ++c) s += lnb[c] * w1[c * 384 + n];
        B1s[n] = s;
    } else if (i < 74880) {                       // conv weight pairs
        int j = i - 37248;
        int c = j / 392, r = j - c * 392;
        int kd = r / 56, q = r - kd * 56;
        int pr8 = q / 7, kw = q - pr8 * 7;
        const float* Wk = dww + c * 343 + kd * 49;
        float lo, hi;
        if (pr8 < 4) {
            int pr = pr8;
            lo = Wk[(2 * pr) * 7 + kw];
            hi = (2 * pr + 1 < 7) ? Wk[(2 * pr + 1) * 7 + kw] : 0.f;
        } else {
            int pr = pr8 - 4;
            lo = (2 * pr - 1 >= 0) ? Wk[(2 * pr - 1) * 7 + kw] : 0.f;
            hi = Wk[(2 * pr) * 7 + kw];
        }
        wpair[j] = pkh(lo, hi);
    }
}

// ---------------------------------------------------------------------------
// K1: depthwise 7x7x7 conv + bias via v_dot2_f32_f16 (unchanged from R2).
// ---------------------------------------------------------------------------
template<int PACKED, int WP>
__global__ __launch_bounds__(256, 5) void dwconv(const float* __restrict__ x,
                                                 const float* __restrict__ dww,
                                                 const float* __restrict__ dwb,
                                                 const u32* __restrict__ wpair,
                                                 u32* cw, u16* o16) {
    __shared__ u32 tile32[7920];                  // 10 * 792
    const int tid = threadIdx.x;
    const int bx = blockIdx.x, c = blockIdx.y, b = blockIdx.z;
    const int d0 = (bx >> 2) * 4, h0 = (bx & 3) * 16;
    const float* xc = x + ((size_t)(b * 96 + c)) * 262144;

    for (int i = tid; i < 7700; i += 256) {
        int pz = i / 770;
        int rem = i - pz * 770;
        int r2 = rem / 70;
        int col = rem - r2 * 70;
        int d = d0 + pz - 3, h = h0 + 2 * r2 - 3, w = col - 3;
        float lo = 0.f, hi = 0.f;
        if (((unsigned)d < 64u) && ((unsigned)w < 64u)) {
            int base = d * 4096 + h * 64 + w;
            if ((unsigned)h < 64u) lo = xc[base];
            if ((unsigned)(h + 1) < 64u) hi = xc[base + 64];
        }
        int a = pz * 792 + r2 * 72 + col;
        int aw = ((((a >> 2) ^ ((a >> 5) & 1)) << 2)) | (a & 3);
        tile32[aw] = pkh(lo, hi);
    }
    __syncthreads();

    const int tx = tid & 7, ty = (tid >> 3) & 7, tz = tid >> 6;
    float a0[8], a1[8];
#pragma unroll
    for (int i = 0; i < 8; ++i) { a0[i] = 0.f; a1[i] = 0.f; }

    for (int kd = 0; kd < 7; ++kd) {
        const u32* wpk = wpair + (c * 7 + kd) * 56;
        const float* Wk = dww + c * 343 + kd * 49;
        const int pz = tz + kd;
#pragma unroll
        for (int pr = 0; pr < 4; ++pr) {
            u32 wa[7], wb[7];
            if (WP == 1) {
#pragma unroll
                for (int kw = 0; kw < 7; ++kw) {
                    wa[kw] = wpk[pr * 7 + kw];
                    wb[kw] = wpk[(pr + 4) * 7 + kw];
                }
            } else {
#pragma unroll
                for (int kw = 0; kw < 7; ++kw) {
                    float la = Wk[(2 * pr) * 7 + kw];
                    float ha = (2 * pr + 1 < 7) ? Wk[(2 * pr + 1) * 7 + kw] : 0.f;
                    float lb = (2 * pr - 1 >= 0) ? Wk[(2 * pr - 1) * 7 + kw] : 0.f;
                    wa[kw] = pkh(la, ha);
                    wb[kw] = pkh(lb, la);
                }
            }
            const int g0 = pz * 198 + (ty + pr) * 18 + (tx << 1);
            u32 rb[16];
#pragma unroll
            for (int k = 0; k < 4; ++k) {
                int g = g0 + k;
                int ga = (g ^ ((g >> 3) & 1)) << 2;
                *(u32x4*)&rb[4 * k] = *(const u32x4*)(tile32 + ga);
            }
#pragma unroll
            for (int kw = 0; kw < 7; ++kw) {
                hf2 va = ash(wa[kw]), vb = ash(wb[kw]);
#pragma unroll
                for (int i = 0; i < 8; ++i) {
                    a0[i] = __builtin_amdgcn_fdot2(ash(rb[kw + i]), va, a0[i], false);
                    a1[i] = __builtin_amdgcn_fdot2(ash(rb[kw + i]), vb, a1[i], false);
                }
            }
        }
    }

    const float bias = dwb[c];
    const int d = d0 + tz;
    const int hA = h0 + 2 * ty;
    if (PACKED == 0) {
        const int p = b * 262144 + d * 4096 + hA * 64 + 8 * tx;
        u32* dst = cw + c * 262144 + (p >> 1);
#pragma unroll
        for (int k = 0; k < 4; ++k)
            dst[k] = (u32)f2bf_rne(a0[2 * k] + bias) | ((u32)f2bf_rne(a0[2 * k + 1] + bias) << 16);
        u32* dst1 = dst + 32;
#pragma unroll
        for (int k = 0; k < 4; ++k)
            dst1[k] = (u32)f2bf_rne(a1[2 * k] + bias) | ((u32)f2bf_rne(a1[2 * k + 1] + bias) << 16);
    } else {
        size_t e = ((size_t)(b * 96 + c)) * 262144 + d * 4096 + hA * 64 + 8 * tx;
#pragma unroll
        for (int i = 0; i < 8; ++i) o16[2 * (e + i) + 1] = f2bf_rne(a0[i] + bias);
#pragma unroll
        for (int i = 0; i < 8; ++i) o16[2 * (e + 64 + i) + 1] = f2bf_rne(a1[i] + bias);
    }
}

// ---------------------------------------------------------------------------
// K2 v2: LN folded into fp8 GEMMs; one barrier; each wave owns a 16-pos tile.
// CWP: 0 = conv-out in ws (bf16 pairs [c][524288 u16]); 1 = hi bytes of d_out.
// WF : 0 = fp8 tables from ws; 1 = build from f32 weights (fallback).
// ---------------------------------------------------------------------------
template<int CWP, int WF>
__global__ __launch_bounds__(1024) void mlp2(const void* cwsrc,
                                             const unsigned char* __restrict__ w1f8,
                                             const unsigned char* __restrict__ w2f8,
                                             const float* __restrict__ B1sg,
                                             const float* __restrict__ w1f,
                                             const float* __restrict__ w2f,
                                             const float* __restrict__ lng,
                                             const float* __restrict__ lnb,
                                             const float* __restrict__ b1g,
                                             const float* __restrict__ b2g,
                                             const float* __restrict__ gam,
                                             const float* __restrict__ x,
                                             float* __restrict__ out) {
    __shared__ __align__(16) unsigned char W1[39936];   // [384 n][stride 104 B] fp8
    __shared__ float B1s[384];
    __shared__ float MISC[192];                         // b2[96] | gamma[96]
    __shared__ __align__(16) unsigned char HS[16][1152]; // per-wave [16 pos][stride 72 B]

    const int tid = threadIdx.x;

    if (WF == 0) {
        for (int i = tid; i < 9216; i += 1024) {        // 384*96/4 u32
            int n = i / 24, q = i - n * 24;
            *(u32*)&W1[n * 104 + q * 4] = ((const u32*)w1f8)[i];
        }
        if (tid < 384) B1s[tid] = B1sg[tid];
    } else {
        for (int i = tid; i < 18432; i += 1024) {
            int n = i / 48, cp = i - n * 48;
            float a = lng[2 * cp] * w1f[(2 * cp) * 384 + n];
            float b = lng[2 * cp + 1] * w1f[(2 * cp + 1) * 384 + n];
            u32 w = (u32)__builtin_amdgcn_cvt_pk_fp8_f32(a, b, 0, false);
            *(u16*)&W1[n * 104 + 2 * cp] = (u16)w;
        }
        if (tid < 384) {
            float s = b1g[tid];
            for (int c = 0; c < 96; ++c) s += lnb[c] * w1f[c * 384 + tid];
            B1s[tid] = s;
        }
    }
    if (tid < 192) MISC[tid] = (tid < 96) ? b2g[tid] : gam[tid - 96];
    __syncthreads();

    const int wv = tid >> 6, lane = tid & 63;
    const int p = lane & 15, G = lane >> 4;
    const int p0 = blockIdx.x * 256 + wv * 16;          // global flat position base
    const int b = p0 >> 18, prel = p0 & 262143;
    unsigned char* hsw = &HS[wv][0];

    // ---- load conv values in A-frag layout: c = kk*32 + G*8 + j, pos = p0 + p
    float v[3][8];
    if (CWP == 0) {
        const u16* cw16 = (const u16*)cwsrc;
#pragma unroll
        for (int kk = 0; kk < 3; ++kk)
#pragma unroll
            for (int j = 0; j < 8; ++j) {
                int c = kk * 32 + G * 8 + j;
                v[kk][j] = bf2f(cw16[(size_t)c * 524288 + p0 + p]);
            }
    } else {
        const u32* ow = (const u32*)cwsrc;
#pragma unroll
        for (int kk = 0; kk < 3; ++kk)
#pragma unroll
            for (int j = 0; j < 8; ++j) {
                int c = kk * 32 + G * 8 + j;
                v[kk][j] = bf2f((u16)(ow[((size_t)(b * 96 + c)) * 262144 + prel + p] >> 16));
            }
    }

    // ---- LN stats across the 4 G-lanes sharing this position
    float s = 0.f, sq = 0.f;
#pragma unroll
    for (int kk = 0; kk < 3; ++kk)
#pragma unroll
        for (int j = 0; j < 8; ++j) { s += v[kk][j]; sq += v[kk][j] * v[kk][j]; }
    s += __shfl_xor(s, 16); sq += __shfl_xor(sq, 16);
    s += __shfl_xor(s, 32); sq += __shfl_xor(sq, 32);
    float mu = s * (1.f / 96.f);
    float rstd = rsqrtf(sq * (1.f / 96.f) - mu * mu + 1e-5f);

    // ---- fp8 A-fragments (normalized; gamma/beta folded into W1/B1s)
    i64 aF[3];
#pragma unroll
    for (int kk = 0; kk < 3; ++kk) {
        u32 lo = 0, hi = 0;
        float n0 = (v[kk][0] - mu) * rstd, n1 = (v[kk][1] - mu) * rstd;
        float n2 = (v[kk][2] - mu) * rstd, n3 = (v[kk][3] - mu) * rstd;
        float n4 = (v[kk][4] - mu) * rstd, n5 = (v[kk][5] - mu) * rstd;
        float n6 = (v[kk][6] - mu) * rstd, n7 = (v[kk][7] - mu) * rstd;
        lo = (u32)__builtin_amdgcn_cvt_pk_fp8_f32(n0, n1, (int)lo, false);
        lo = (u32)__builtin_amdgcn_cvt_pk_fp8_f32(n2, n3, (int)lo, true);
        hi = (u32)__builtin_amdgcn_cvt_pk_fp8_f32(n4, n5, (int)hi, false);
        hi = (u32)__builtin_amdgcn_cvt_pk_fp8_f32(n6, n7, (int)hi, true);
        aF[kk] = mk64(lo, hi);
    }

    f32x4 acc[6];
#pragma unroll
    for (int i = 0; i < 6; ++i) acc[i] = f32x4{0.f, 0.f, 0.f, 0.f};

    for (int j = 0; j < 6; ++j) {
        // GEMM1 (swapped): D[n][pos] — lane keeps its own position's outputs
        f32x4 c1[4];
#pragma unroll
        for (int nt = 0; nt < 4; ++nt) {
            int n16 = j * 4 + nt;
            c1[nt] = f32x4{0.f, 0.f, 0.f, 0.f};
#pragma unroll
            for (int kk = 0; kk < 3; ++kk) {
                i64 wfrag = *(const i64*)&W1[(n16 * 16 + p) * 104 + kk * 32 + G * 8];
                c1[nt] = __builtin_amdgcn_mfma_f32_16x16x32_fp8_fp8(wfrag, aF[kk], c1[nt], 0, 0, 0);
            }
        }
        // bias (LN-folded) + GELU -> fp8 -> per-wave LDS scratch
#pragma unroll
        for (int nt = 0; nt < 4; ++nt) {
            f32x4 bb = *(const f32x4*)&B1s[(j * 4 + nt) * 16 + 4 * G];
            float g0 = gelu_fast(c1[nt][0] + bb[0]);
            float g1 = gelu_fast(c1[nt][1] + bb[1]);
            float g2 = gelu_fast(c1[nt][2] + bb[2]);
            float g3 = gelu_fast(c1[nt][3] + bb[3]);
            u32 w = 0;
            w = (u32)__builtin_amdgcn_cvt_pk_fp8_f32(g0, g1, (int)w, false);
            w = (u32)__builtin_amdgcn_cvt_pk_fp8_f32(g2, g3, (int)w, true);
            *(u32*)&hsw[p * 72 + nt * 16 + 4 * G] = w;
        }
        asm volatile("s_waitcnt lgkmcnt(0)" ::: "memory");
        __builtin_amdgcn_sched_barrier(0);

        i64 hF[2];
#pragma unroll
        for (int kkj = 0; kkj < 2; ++kkj)
            hF[kkj] = *(const i64*)&hsw[p * 72 + kkj * 32 + G * 8];

        // GEMM2: D[pos][c], accumulate over n
#pragma unroll
        for (int ct = 0; ct < 6; ++ct) {
#pragma unroll
            for (int kkj = 0; kkj < 2; ++kkj) {
                i64 w2frag;
                if (WF == 0) {
                    w2frag = *(const i64*)&w2f8[(size_t)(ct * 16 + p) * 384 + (j * 2 + kkj) * 32 + G * 8];
                } else {
                    int c = ct * 16 + p;
                    int nb = (j * 2 + kkj) * 32 + G * 8;
                    u32 lo = 0, hi = 0;
                    lo = (u32)__builtin_amdgcn_cvt_pk_fp8_f32(w2f[(nb + 0) * 96 + c], w2f[(nb + 1) * 96 + c], (int)lo, false);
                    lo = (u32)__builtin_amdgcn_cvt_pk_fp8_f32(w2f[(nb + 2) * 96 + c], w2f[(nb + 3) * 96 + c], (int)lo, true);
                    hi = (u32)__builtin_amdgcn_cvt_pk_fp8_f32(w2f[(nb + 4) * 96 + c], w2f[(nb + 5) * 96 + c], (int)hi, false);
                    hi = (u32)__builtin_amdgcn_cvt_pk_fp8_f32(w2f[(nb + 6) * 96 + c], w2f[(nb + 7) * 96 + c], (int)hi, true);
                    w2frag = mk64(lo, hi);
                }
                acc[ct] = __builtin_amdgcn_mfma_f32_16x16x32_fp8_fp8(hF[kkj], w2frag, acc[ct], 0, 0, 0);
            }
        }
    }

    // ---- epilogue: bias2 + gamma + residual, vectorized f32x4
#pragma unroll
    for (int ct = 0; ct < 6; ++ct) {
        int c = ct * 16 + p;
        size_t xi = ((size_t)(b * 96 + c)) * 262144 + prel + G * 4;
        f32x4 xv = *(const f32x4*)&x[xi];
        float b2c = MISC[c], gc = MISC[96 + c];
        f32x4 o;
#pragma unroll
        for (int r = 0; r < 4; ++r) o[r] = (acc[ct][r] + b2c) * gc + xv[r];
        *(f32x4*)&out[xi] = o;
    }
}

// ---------------------------------------------------------------------------
extern "C" void kernel_launch(void* const* d_in, const int* in_sizes, int n_in,
                              void* d_out, int out_size, void* d_ws, size_t ws_size,
                              hipStream_t stream) {
    const float* x   = (const float*)d_in[0];
    const float* dww = (const float*)d_in[1];
    const float* dwb = (const float*)d_in[2];
    const float* lng = (const float*)d_in[3];
    const float* lnb = (const float*)d_in[4];
    const float* w1  = (const float*)d_in[5];
    const float* b1  = (const float*)d_in[6];
    const float* w2  = (const float*)d_in[7];
    const float* b2  = (const float*)d_in[8];
    const float* gam = (const float*)d_in[9];
    float* out = (float*)d_out;

    // ws layout: w1f8 @0 (36864) | w2f8 @36864 (36864) | B1s @73728 (1536)
    //            | wpair @75264 (150528) | cw @225792 (100663296)
    const size_t NEED_W = 225792;
    const size_t NEED_FULL = NEED_W + 100663296ull;
    const bool wsW = ws_size >= NEED_W;
    const bool wsCW = ws_size >= NEED_FULL;

    unsigned char* w1f8 = (unsigned char*)d_ws;
    unsigned char* w2f8 = (unsigned char*)d_ws + 36864;
    float* B1s = (float*)((char*)d_ws + 73728);
    u32* wpair = (u32*)((char*)d_ws + 75264);
    u32* cw = (u32*)((char*)d_ws + 225792);

    if (wsW)
        hipLaunchKernelGGL(prep_weights, dim3(293), dim3(256), 0, stream,
                           w1, w2, dww, lng, lnb, b1, w1f8, w2f8, B1s, wpair);

    dim3 g1(64, 96, 2), blk(256);
    if (wsCW)
        hipLaunchKernelGGL((dwconv<0, 1>), g1, blk, 0, stream, x, dww, dwb, wpair, cw, (u16*)d_out);
    else if (wsW)
        hipLaunchKernelGGL((dwconv<1, 1>), g1, blk, 0, stream, x, dww, dwb, wpair, cw, (u16*)d_out);
    else
        hipLaunchKernelGGL((dwconv<1, 0>), g1, blk, 0, stream, x, dww, dwb, wpair, cw, (u16*)d_out);

    dim3 g2(2048), blk2(1024);
    if (wsCW)
        hipLaunchKernelGGL((mlp2<0, 0>), g2, blk2, 0, stream, (const void*)cw,
                           w1f8, w2f8, B1s, w1, w2, lng, lnb, b1, b2, gam, x, out);
    else if (wsW)
        hipLaunchKernelGGL((mlp2<1, 0>), g2, blk2, 0, stream, (const void*)d_out,
                           w1f8, w2f8, B1s, w1, w2, lng, lnb, b1, b2, gam, x, out);
    else
        hipLaunchKernelGGL((mlp2<1, 1>), g2, blk2, 0, stream, (const void*)d_out,
                           w1f8, w2f8, B1s, w1, w2, lng, lnb, b1, b2, gam, x, out);
}